// Round 1
// baseline (602.133 us; speedup 1.0000x reference)
//
#include <hip/hip_runtime.h>

// Problem constants
#define NN    8192          // N
#define DD    384           // dim
#define RR    64            // rank
#define BNROW 131072        // B*N
#define NGRP  2048          // B*g

__device__ __forceinline__ float silu_f(float x) {
    return x / (1.0f + __expf(-x));
}

// 4x4 register-tile MAC from two stride-65 LDS arrays (contraction-major)
#define MAC16(AS, BS, ACC, K) \
  { float a0_=AS[(K)*65+4*ty+0], a1_=AS[(K)*65+4*ty+1], a2_=AS[(K)*65+4*ty+2], a3_=AS[(K)*65+4*ty+3]; \
    float b0_=BS[(K)*65+4*tx+0], b1_=BS[(K)*65+4*tx+1], b2_=BS[(K)*65+4*tx+2], b3_=BS[(K)*65+4*tx+3]; \
    ACC[0][0]+=a0_*b0_; ACC[0][1]+=a0_*b1_; ACC[0][2]+=a0_*b2_; ACC[0][3]+=a0_*b3_; \
    ACC[1][0]+=a1_*b0_; ACC[1][1]+=a1_*b1_; ACC[1][2]+=a1_*b2_; ACC[1][3]+=a1_*b3_; \
    ACC[2][0]+=a2_*b0_; ACC[2][1]+=a2_*b1_; ACC[2][2]+=a2_*b2_; ACC[2][3]+=a2_*b3_; \
    ACC[3][0]+=a3_*b0_; ACC[3][1]+=a3_*b1_; ACC[3][2]+=a3_*b2_; ACC[3][3]+=a3_*b3_; }

// ---------------------------------------------------------------------------
// Kernel A: h = silu(input @ Wd^T + bd)   input [BN,384], Wd [64,384], h [BN,64]
// One block = 64 rows x 64 cols, K staged in 6 chunks of 64.
// ---------------------------------------------------------------------------
__global__ __launch_bounds__(256) void kA(const float* __restrict__ in,
                                          const float* __restrict__ Wd,
                                          const float* __restrict__ bd,
                                          float* __restrict__ h) {
    __shared__ float InT[64*65];   // InT[k][m] = input[m0+m][kc*64+k]
    __shared__ float WdT[64*65];   // WdT[k][j] = Wd[j][kc*64+k]
    const int tid = threadIdx.x;
    const int tx = tid & 15, ty = tid >> 4;
    const int m0 = blockIdx.x * 64;
    float acc[4][4] = {};
    for (int kc = 0; kc < 6; ++kc) {
        for (int it = 0; it < 4; ++it) {
            int idx = it * 256 + tid;        // 0..1023 float4 slots
            int r   = idx >> 4;              // 0..63  (row m, or row j of Wd)
            int kq  = idx & 15;              // float4 index along k
            float4 v = *(const float4*)(in + (m0 + r) * DD + kc * 64 + kq * 4);
            InT[(kq*4+0)*65 + r] = v.x;
            InT[(kq*4+1)*65 + r] = v.y;
            InT[(kq*4+2)*65 + r] = v.z;
            InT[(kq*4+3)*65 + r] = v.w;
            float4 w = *(const float4*)(Wd + r * DD + kc * 64 + kq * 4);
            WdT[(kq*4+0)*65 + r] = w.x;
            WdT[(kq*4+1)*65 + r] = w.y;
            WdT[(kq*4+2)*65 + r] = w.z;
            WdT[(kq*4+3)*65 + r] = w.w;
        }
        __syncthreads();
        #pragma unroll 8
        for (int k = 0; k < 64; ++k) {
            MAC16(InT, WdT, acc, k);
        }
        __syncthreads();
    }
    const float bj0 = bd[4*tx+0], bj1 = bd[4*tx+1], bj2 = bd[4*tx+2], bj3 = bd[4*tx+3];
    for (int i = 0; i < 4; ++i) {
        float4 o;
        o.x = silu_f(acc[i][0] + bj0);
        o.y = silu_f(acc[i][1] + bj1);
        o.z = silu_f(acc[i][2] + bj2);
        o.w = silu_f(acc[i][3] + bj3);
        *(float4*)(h + (m0 + 4*ty + i) * 64 + 4*tx) = o;
    }
}

// ---------------------------------------------------------------------------
// Kernel B: per (b,g) group (one block each):
//   X[t][r]  = h[b, idx0[b, g*64+t], r]           (gather)
//   f = U^T X ; f += silu(LN_r(f) @ Wa^T + ba) ; y = U f ; y1[b, g*64+s, r] = y
// U = sub_U[1,b,g]  [t][s] (t-major, s contiguous)
// ---------------------------------------------------------------------------
__global__ __launch_bounds__(256) void kB(const float* __restrict__ h,
                                          const float* __restrict__ U1,    // + branch-1 offset
                                          const int*   __restrict__ idx0,
                                          const float* __restrict__ Wa,
                                          const float* __restrict__ ba,
                                          const float* __restrict__ gamma,
                                          const float* __restrict__ beta,
                                          float* __restrict__ y1) {
    __shared__ float UA[64*65];   // U[t][s]  ->  LNT[r][s]  ->  At[t][s]=U[s][t]
    __shared__ float XF[64*65];   // X[t][r]  ->  F[t][r]
    __shared__ float WT[64*65];   // WaT[r][q] = Wa[q][r]
    const int tid = threadIdx.x;
    const int tx = tid & 15, ty = tid >> 4;
    const int bg = blockIdx.x;          // b*128 + g
    const int b  = bg >> 7;
    const float* U = U1 + bg * 4096;

    for (int it = 0; it < 4; ++it) {
        int idx = it * 256 + tid;
        int row = idx >> 4;             // t (or q for Wa)
        int kq  = idx & 15;
        float4 u = *(const float4*)(U + row * 64 + kq * 4);
        UA[row*65 + kq*4+0] = u.x;      // native U[t][s]
        UA[row*65 + kq*4+1] = u.y;
        UA[row*65 + kq*4+2] = u.z;
        UA[row*65 + kq*4+3] = u.w;
        int src = idx0[bg * 64 + row];
        float4 x = *(const float4*)(h + (b * NN + src) * 64 + kq * 4);
        XF[row*65 + kq*4+0] = x.x;      // X[t][r]
        XF[row*65 + kq*4+1] = x.y;
        XF[row*65 + kq*4+2] = x.z;
        XF[row*65 + kq*4+3] = x.w;
        float4 w = *(const float4*)(Wa + row * 64 + kq * 4);
        WT[(kq*4+0)*65 + row] = w.x;    // WaT[r][q]
        WT[(kq*4+1)*65 + row] = w.y;
        WT[(kq*4+2)*65 + row] = w.z;
        WT[(kq*4+3)*65 + row] = w.w;
    }
    __syncthreads();

    // f[s][r] = sum_t U[t][s] * X[t][r]
    float f[4][4] = {};
    #pragma unroll 8
    for (int t = 0; t < 64; ++t) {
        MAC16(UA, XF, f, t);
    }
    __syncthreads();   // U reads done; UA reusable

    // LayerNorm over r (columns). Rows 4*ty+i live across lanes sharing ty: tx bits.
    const float g0 = gamma[4*tx+0], g1 = gamma[4*tx+1], g2 = gamma[4*tx+2], g3 = gamma[4*tx+3];
    const float e0 = beta[4*tx+0],  e1 = beta[4*tx+1],  e2 = beta[4*tx+2],  e3 = beta[4*tx+3];
    float lnv[4][4];
    #pragma unroll
    for (int i = 0; i < 4; ++i) {
        float sm = f[i][0] + f[i][1] + f[i][2] + f[i][3];
        float sq = f[i][0]*f[i][0] + f[i][1]*f[i][1] + f[i][2]*f[i][2] + f[i][3]*f[i][3];
        #pragma unroll
        for (int mask = 1; mask <= 8; mask <<= 1) {
            sm += __shfl_xor(sm, mask, 64);
            sq += __shfl_xor(sq, mask, 64);
        }
        float mean = sm * 0.015625f;
        float var  = sq * 0.015625f - mean * mean;
        float rstd = rsqrtf(var + 1e-5f);
        lnv[i][0] = (f[i][0] - mean) * rstd * g0 + e0;
        lnv[i][1] = (f[i][1] - mean) * rstd * g1 + e1;
        lnv[i][2] = (f[i][2] - mean) * rstd * g2 + e2;
        lnv[i][3] = (f[i][3] - mean) * rstd * g3 + e3;
    }
    // LNT[r][s] into UA (transpose write; few, tolerable conflicts)
    #pragma unroll
    for (int i = 0; i < 4; ++i)
        #pragma unroll
        for (int j = 0; j < 4; ++j)
            UA[(4*tx+j)*65 + (4*ty+i)] = lnv[i][j];
    __syncthreads();

    // a[s][q] = sum_r LNT[r][s] * WaT[r][q]
    float a[4][4] = {};
    #pragma unroll 8
    for (int r = 0; r < 64; ++r) {
        MAC16(UA, WT, a, r);
    }
    const float a0 = ba[4*tx+0], a1 = ba[4*tx+1], a2 = ba[4*tx+2], a3 = ba[4*tx+3];
    #pragma unroll
    for (int i = 0; i < 4; ++i) {
        f[i][0] += silu_f(a[i][0] + a0);
        f[i][1] += silu_f(a[i][1] + a1);
        f[i][2] += silu_f(a[i][2] + a2);
        f[i][3] += silu_f(a[i][3] + a3);
    }
    __syncthreads();   // LNT reads done; UA reusable; XF reusable

    // Restage At[t][s] = U[s][t] into UA (re-read global, L2-hot); F[t][r] into XF
    for (int it = 0; it < 4; ++it) {
        int idx = it * 256 + tid;
        int row = idx >> 4;
        int kq  = idx & 15;
        float4 u = *(const float4*)(U + row * 64 + kq * 4);  // U[row][kq*4+d]
        UA[(kq*4+0)*65 + row] = u.x;    // At[c][row] = U[row][c]
        UA[(kq*4+1)*65 + row] = u.y;
        UA[(kq*4+2)*65 + row] = u.z;
        UA[(kq*4+3)*65 + row] = u.w;
    }
    #pragma unroll
    for (int i = 0; i < 4; ++i)
        #pragma unroll
        for (int j = 0; j < 4; ++j)
            XF[(4*ty+i)*65 + 4*tx+j] = f[i][j];
    __syncthreads();

    // y[s][r] = sum_t U[s][t] * F[t][r] = sum_t At[t][s] * F[t][r]
    float y[4][4] = {};
    #pragma unroll 8
    for (int t = 0; t < 64; ++t) {
        MAC16(UA, XF, y, t);
    }
    for (int i = 0; i < 4; ++i) {
        float4 o;
        o.x = y[i][0]; o.y = y[i][1]; o.z = y[i][2]; o.w = y[i][3];
        *(float4*)(y1 + (bg * 64 + 4*ty + i) * 64 + 4*tx) = o;
    }
}

// ---------------------------------------------------------------------------
// Kernel C: out = (gather(y1, idx1) + y1 + h) @ Wu^T + bu
// Wu [384,64]; one block = 64 rows x 384 cols (6 col chunks), K = 64.
// ---------------------------------------------------------------------------
__global__ __launch_bounds__(256) void kC(const float* __restrict__ h,
                                          const float* __restrict__ y1,
                                          const int*   __restrict__ idx1,
                                          const float* __restrict__ Wu,
                                          const float* __restrict__ bu,
                                          float* __restrict__ out) {
    __shared__ float Hs[64*65];    // Hs[k][m]  = hsum[m0+m][k]
    __shared__ float WuT[64*65];   // WuT[k][j] = Wu[jc*64+j][k]
    const int tid = threadIdx.x;
    const int tx = tid & 15, ty = tid >> 4;
    const int m0 = blockIdx.x * 64;
    const int b  = m0 >> 13;                 // m0 / 8192
    const int n0 = m0 & (NN - 1);

    for (int it = 0; it < 4; ++it) {
        int idx = it * 256 + tid;
        int r   = idx >> 4;                  // local row
        int kq  = idx & 15;
        int i1  = idx1[b * NN + n0 + r];
        float4 ya = *(const float4*)(y1 + (b * NN + i1) * 64 + kq * 4);
        float4 yb = *(const float4*)(y1 + (m0 + r) * 64 + kq * 4);
        float4 hh = *(const float4*)(h  + (m0 + r) * 64 + kq * 4);
        Hs[(kq*4+0)*65 + r] = ya.x + yb.x + hh.x;
        Hs[(kq*4+1)*65 + r] = ya.y + yb.y + hh.y;
        Hs[(kq*4+2)*65 + r] = ya.z + yb.z + hh.z;
        Hs[(kq*4+3)*65 + r] = ya.w + yb.w + hh.w;
    }
    __syncthreads();

    for (int jc = 0; jc < 6; ++jc) {
        for (int it = 0; it < 4; ++it) {
            int idx = it * 256 + tid;
            int r   = idx >> 4;              // local col j
            int kq  = idx & 15;
            float4 w = *(const float4*)(Wu + (jc * 64 + r) * 64 + kq * 4);
            WuT[(kq*4+0)*65 + r] = w.x;
            WuT[(kq*4+1)*65 + r] = w.y;
            WuT[(kq*4+2)*65 + r] = w.z;
            WuT[(kq*4+3)*65 + r] = w.w;
        }
        __syncthreads();
        float acc[4][4] = {};
        #pragma unroll 8
        for (int k = 0; k < 64; ++k) {
            MAC16(Hs, WuT, acc, k);
        }
        const float b0 = bu[jc*64 + 4*tx+0], b1 = bu[jc*64 + 4*tx+1];
        const float b2 = bu[jc*64 + 4*tx+2], b3 = bu[jc*64 + 4*tx+3];
        for (int i = 0; i < 4; ++i) {
            float4 o;
            o.x = acc[i][0] + b0;
            o.y = acc[i][1] + b1;
            o.z = acc[i][2] + b2;
            o.w = acc[i][3] + b3;
            *(float4*)(out + (m0 + 4*ty + i) * DD + jc * 64 + 4*tx) = o;
        }
        __syncthreads();
    }
}

// ---------------------------------------------------------------------------
extern "C" void kernel_launch(void* const* d_in, const int* in_sizes, int n_in,
                              void* d_out, int out_size, void* d_ws, size_t ws_size,
                              hipStream_t stream) {
    const float* input = (const float*)d_in[0];
    const float* subU  = (const float*)d_in[1];
    const int*   idx   = (const int*)  d_in[2];
    const float* Wd    = (const float*)d_in[3];
    const float* bd    = (const float*)d_in[4];
    const float* Wu    = (const float*)d_in[5];
    const float* bu    = (const float*)d_in[6];
    const float* Wa    = (const float*)d_in[7];
    const float* ba    = (const float*)d_in[8];
    const float* gamma = (const float*)d_in[9];
    const float* beta  = (const float*)d_in[10];
    float* out = (float*)d_out;

    float* h  = (float*)d_ws;           // [BN, 64]  = 8388608 floats
    float* y1 = h + 8388608;            // [BN, 64]

    const float* U1   = subU + 8388608; // sub_U[1] : branch-1 slice (branch 0 is dead code)
    const int*   idx0 = idx;
    const int*   idx1 = idx + BNROW;

    kA<<<2048, 256, 0, stream>>>(input, Wd, bd, h);
    kB<<<2048, 256, 0, stream>>>(h, U1, idx0, Wa, ba, gamma, beta, y1);
    kC<<<2048, 256, 0, stream>>>(h, y1, idx1, Wu, bu, out);
}

// Round 2
// 513.054 us; speedup vs baseline: 1.1736x; 1.1736x over previous
//
#include <hip/hip_runtime.h>

// Problem constants
#define NN    8192          // N
#define DD    384           // dim
#define RR    64            // rank
#define BNROW 131072        // B*N
#define NGRP  2048          // B*g

typedef __attribute__((ext_vector_type(8))) short short8;   // 8 bf16 (A/B frag)
typedef __attribute__((ext_vector_type(4))) float floatx4;  // C/D frag

__device__ __forceinline__ float silu_f(float x) {
    return x / (1.0f + __expf(-x));
}

// pack two fp32 -> two bf16 (RNE) in one uint
__device__ __forceinline__ unsigned bf2(float a, float b) {
    unsigned ua = __float_as_uint(a), ub = __float_as_uint(b);
    ua = (ua + 0x7fffu + ((ua >> 16) & 1u)) >> 16;
    ub = (ub + 0x7fffu + ((ub >> 16) & 1u)) >> 16;
    return ua | (ub << 16);
}

union S8 { unsigned u[4]; short8 s; };

// ---------------------------------------------------------------------------
// Kernel A (MFMA): h = silu(input @ Wd^T + bd)
// input [BN,384] fp32, Wd [64,384] -> staged bf16 LDS as WdB[n][k] (pad 392).
// Block = 64 rows (4 waves x 16), grid 2048. Wave: 16 rows x 64 cols,
// K = 384 = 12 MFMA k-steps. A-frags converted fp32->bf16 in registers.
// ---------------------------------------------------------------------------
__global__ __launch_bounds__(256) void kA(const float* __restrict__ in,
                                          const float* __restrict__ Wd,
                                          const float* __restrict__ bd,
                                          float* __restrict__ h) {
    __shared__ unsigned short WdB[64 * 392];   // [n][k], stride 392 (784B = 196w ≡ 4 mod 32)
    const int tid = threadIdx.x;
    // stage Wd (64x384 fp32 = 6144 float4), coalesced
    for (int i = tid; i < 6144; i += 256) {
        int n = i / 96, c4 = i - n * 96;               // 96 float4 per row
        float4 v = *(const float4*)(Wd + n * DD + c4 * 4);
        *(uint2*)&WdB[n * 392 + c4 * 4] = make_uint2(bf2(v.x, v.y), bf2(v.z, v.w));
    }
    __syncthreads();

    const int lane = tid & 63, w = tid >> 6;
    const int quad = lane >> 4, lr = lane & 15;
    const int grow = blockIdx.x * 64 + w * 16 + lr;    // this lane's A-row
    const float* arow = in + grow * DD;

    floatx4 acc[4] = {};                                // 4 n-tiles of 16 cols
    #pragma unroll
    for (int ks = 0; ks < 12; ++ks) {
        float4 p = *(const float4*)(arow + ks * 32 + quad * 8);
        float4 q = *(const float4*)(arow + ks * 32 + quad * 8 + 4);
        S8 a;
        a.u[0] = bf2(p.x, p.y); a.u[1] = bf2(p.z, p.w);
        a.u[2] = bf2(q.x, q.y); a.u[3] = bf2(q.z, q.w);
        #pragma unroll
        for (int n = 0; n < 4; ++n) {
            const short8 b = *(const short8*)&WdB[(n * 16 + lr) * 392 + ks * 32 + quad * 8];
            acc[n] = __builtin_amdgcn_mfma_f32_16x16x32_bf16(a.s, b, acc[n], 0, 0, 0);
        }
    }
    // D layout: row = quad*4 + i, col = n*16 + lr
    const int orow0 = blockIdx.x * 64 + w * 16 + quad * 4;
    #pragma unroll
    for (int n = 0; n < 4; ++n) {
        float bb = bd[n * 16 + lr];
        #pragma unroll
        for (int i = 0; i < 4; ++i)
            h[(orow0 + i) * 64 + n * 16 + lr] = silu_f(acc[n][i] + bb);
    }
}

// ---------------------------------------------------------------------------
// Kernel B (unchanged fp32 register-tiled): per (b,g) group, one block:
//   X = gather(h, idx0); f = U^T X; f += silu(LN_r(f) @ Wa^T + ba); y1 = U f
// ---------------------------------------------------------------------------
#define MAC16(AS, BS, ACC, K) \
  { float a0_=AS[(K)*65+4*ty+0], a1_=AS[(K)*65+4*ty+1], a2_=AS[(K)*65+4*ty+2], a3_=AS[(K)*65+4*ty+3]; \
    float b0_=BS[(K)*65+4*tx+0], b1_=BS[(K)*65+4*tx+1], b2_=BS[(K)*65+4*tx+2], b3_=BS[(K)*65+4*tx+3]; \
    ACC[0][0]+=a0_*b0_; ACC[0][1]+=a0_*b1_; ACC[0][2]+=a0_*b2_; ACC[0][3]+=a0_*b3_; \
    ACC[1][0]+=a1_*b0_; ACC[1][1]+=a1_*b1_; ACC[1][2]+=a1_*b2_; ACC[1][3]+=a1_*b3_; \
    ACC[2][0]+=a2_*b0_; ACC[2][1]+=a2_*b1_; ACC[2][2]+=a2_*b2_; ACC[2][3]+=a2_*b3_; \
    ACC[3][0]+=a3_*b0_; ACC[3][1]+=a3_*b1_; ACC[3][2]+=a3_*b2_; ACC[3][3]+=a3_*b3_; }

__global__ __launch_bounds__(256) void kB(const float* __restrict__ h,
                                          const float* __restrict__ U1,
                                          const int*   __restrict__ idx0,
                                          const float* __restrict__ Wa,
                                          const float* __restrict__ ba,
                                          const float* __restrict__ gamma,
                                          const float* __restrict__ beta,
                                          float* __restrict__ y1) {
    __shared__ float UA[64*65];
    __shared__ float XF[64*65];
    __shared__ float WT[64*65];
    const int tid = threadIdx.x;
    const int tx = tid & 15, ty = tid >> 4;
    const int bg = blockIdx.x;
    const int b  = bg >> 7;
    const float* U = U1 + bg * 4096;

    for (int it = 0; it < 4; ++it) {
        int idx = it * 256 + tid;
        int row = idx >> 4;
        int kq  = idx & 15;
        float4 u = *(const float4*)(U + row * 64 + kq * 4);
        UA[row*65 + kq*4+0] = u.x;
        UA[row*65 + kq*4+1] = u.y;
        UA[row*65 + kq*4+2] = u.z;
        UA[row*65 + kq*4+3] = u.w;
        int src = idx0[bg * 64 + row];
        float4 x = *(const float4*)(h + (b * NN + src) * 64 + kq * 4);
        XF[row*65 + kq*4+0] = x.x;
        XF[row*65 + kq*4+1] = x.y;
        XF[row*65 + kq*4+2] = x.z;
        XF[row*65 + kq*4+3] = x.w;
        float4 w = *(const float4*)(Wa + row * 64 + kq * 4);
        WT[(kq*4+0)*65 + row] = w.x;
        WT[(kq*4+1)*65 + row] = w.y;
        WT[(kq*4+2)*65 + row] = w.z;
        WT[(kq*4+3)*65 + row] = w.w;
    }
    __syncthreads();

    float f[4][4] = {};
    #pragma unroll 8
    for (int t = 0; t < 64; ++t) {
        MAC16(UA, XF, f, t);
    }
    __syncthreads();

    const float g0 = gamma[4*tx+0], g1 = gamma[4*tx+1], g2 = gamma[4*tx+2], g3 = gamma[4*tx+3];
    const float e0 = beta[4*tx+0],  e1 = beta[4*tx+1],  e2 = beta[4*tx+2],  e3 = beta[4*tx+3];
    float lnv[4][4];
    #pragma unroll
    for (int i = 0; i < 4; ++i) {
        float sm = f[i][0] + f[i][1] + f[i][2] + f[i][3];
        float sq = f[i][0]*f[i][0] + f[i][1]*f[i][1] + f[i][2]*f[i][2] + f[i][3]*f[i][3];
        #pragma unroll
        for (int mask = 1; mask <= 8; mask <<= 1) {
            sm += __shfl_xor(sm, mask, 64);
            sq += __shfl_xor(sq, mask, 64);
        }
        float mean = sm * 0.015625f;
        float var  = sq * 0.015625f - mean * mean;
        float rstd = rsqrtf(var + 1e-5f);
        lnv[i][0] = (f[i][0] - mean) * rstd * g0 + e0;
        lnv[i][1] = (f[i][1] - mean) * rstd * g1 + e1;
        lnv[i][2] = (f[i][2] - mean) * rstd * g2 + e2;
        lnv[i][3] = (f[i][3] - mean) * rstd * g3 + e3;
    }
    #pragma unroll
    for (int i = 0; i < 4; ++i)
        #pragma unroll
        for (int j = 0; j < 4; ++j)
            UA[(4*tx+j)*65 + (4*ty+i)] = lnv[i][j];
    __syncthreads();

    float a[4][4] = {};
    #pragma unroll 8
    for (int r = 0; r < 64; ++r) {
        MAC16(UA, WT, a, r);
    }
    const float a0 = ba[4*tx+0], a1 = ba[4*tx+1], a2 = ba[4*tx+2], a3 = ba[4*tx+3];
    #pragma unroll
    for (int i = 0; i < 4; ++i) {
        f[i][0] += silu_f(a[i][0] + a0);
        f[i][1] += silu_f(a[i][1] + a1);
        f[i][2] += silu_f(a[i][2] + a2);
        f[i][3] += silu_f(a[i][3] + a3);
    }
    __syncthreads();

    for (int it = 0; it < 4; ++it) {
        int idx = it * 256 + tid;
        int row = idx >> 4;
        int kq  = idx & 15;
        float4 u = *(const float4*)(U + row * 64 + kq * 4);
        UA[(kq*4+0)*65 + row] = u.x;
        UA[(kq*4+1)*65 + row] = u.y;
        UA[(kq*4+2)*65 + row] = u.z;
        UA[(kq*4+3)*65 + row] = u.w;
    }
    #pragma unroll
    for (int i = 0; i < 4; ++i)
        #pragma unroll
        for (int j = 0; j < 4; ++j)
            XF[(4*ty+i)*65 + 4*tx+j] = f[i][j];
    __syncthreads();

    float y[4][4] = {};
    #pragma unroll 8
    for (int t = 0; t < 64; ++t) {
        MAC16(UA, XF, y, t);
    }
    for (int i = 0; i < 4; ++i) {
        float4 o;
        o.x = y[i][0]; o.y = y[i][1]; o.z = y[i][2]; o.w = y[i][3];
        *(float4*)(y1 + (bg * 64 + 4*ty + i) * 64 + 4*tx) = o;
    }
}

// ---------------------------------------------------------------------------
// Kernel C (MFMA): out = (gather(y1, idx1) + y1 + h) @ Wu^T + bu
// Wu [384,64] -> staged bf16 LDS WuB[n][k] (pad 72). X rows summed+converted
// to bf16 LDS Xs[m][k] (pad 72). Block = 64 rows, grid 2048.
// Wave: 16 rows x 384 cols = 24 n-tiles x 2 k-steps.
// ---------------------------------------------------------------------------
__global__ __launch_bounds__(256) void kC(const float* __restrict__ h,
                                          const float* __restrict__ y1,
                                          const int*   __restrict__ idx1,
                                          const float* __restrict__ Wu,
                                          const float* __restrict__ bu,
                                          float* __restrict__ out) {
    __shared__ unsigned short WuB[384 * 72];  // [n][k], stride 72 (144B = 36w ≡ 4 mod 32)
    __shared__ unsigned short Xs[64 * 72];    // [m][k]
    const int tid = threadIdx.x;
    const int m0 = blockIdx.x * 64;
    const int b  = m0 >> 13;
    const int n0 = m0 & (NN - 1);

    // stage Wu (384x64 fp32 = 6144 float4), coalesced
    for (int i = tid; i < 6144; i += 256) {
        int n = i >> 4, c4 = i & 15;                   // 16 float4 per row
        float4 v = *(const float4*)(Wu + n * 64 + c4 * 4);
        *(uint2*)&WuB[n * 72 + c4 * 4] = make_uint2(bf2(v.x, v.y), bf2(v.z, v.w));
    }
    // stage X = gather(y1) + y1 + h, convert to bf16
    #pragma unroll
    for (int it = 0; it < 4; ++it) {
        int idx = it * 256 + tid;
        int r = idx >> 4, kq = idx & 15;
        int i1 = idx1[b * NN + n0 + r];
        const float4 ya = *(const float4*)(y1 + (b * NN + i1) * 64 + kq * 4);
        const float4 yb = *(const float4*)(y1 + (m0 + r) * 64 + kq * 4);
        const float4 hh = *(const float4*)(h  + (m0 + r) * 64 + kq * 4);
        *(uint2*)&Xs[r * 72 + kq * 4] =
            make_uint2(bf2(ya.x + yb.x + hh.x, ya.y + yb.y + hh.y),
                       bf2(ya.z + yb.z + hh.z, ya.w + yb.w + hh.w));
    }
    __syncthreads();

    const int lane = tid & 63, w = tid >> 6;
    const int quad = lane >> 4, lr = lane & 15;
    const short8 a0 = *(const short8*)&Xs[(w * 16 + lr) * 72 + quad * 8];
    const short8 a1 = *(const short8*)&Xs[(w * 16 + lr) * 72 + 32 + quad * 8];
    const int orow0 = m0 + w * 16 + quad * 4;

    #pragma unroll
    for (int nt = 0; nt < 24; ++nt) {
        const short8 b0 = *(const short8*)&WuB[(nt * 16 + lr) * 72 + quad * 8];
        const short8 b1 = *(const short8*)&WuB[(nt * 16 + lr) * 72 + 32 + quad * 8];
        floatx4 d = {};
        d = __builtin_amdgcn_mfma_f32_16x16x32_bf16(a0, b0, d, 0, 0, 0);
        d = __builtin_amdgcn_mfma_f32_16x16x32_bf16(a1, b1, d, 0, 0, 0);
        const float bb = bu[nt * 16 + lr];
        #pragma unroll
        for (int i = 0; i < 4; ++i)
            out[(orow0 + i) * DD + nt * 16 + lr] = d[i] + bb;
    }
}

// ---------------------------------------------------------------------------
extern "C" void kernel_launch(void* const* d_in, const int* in_sizes, int n_in,
                              void* d_out, int out_size, void* d_ws, size_t ws_size,
                              hipStream_t stream) {
    const float* input = (const float*)d_in[0];
    const float* subU  = (const float*)d_in[1];
    const int*   idx   = (const int*)  d_in[2];
    const float* Wd    = (const float*)d_in[3];
    const float* bd    = (const float*)d_in[4];
    const float* Wu    = (const float*)d_in[5];
    const float* bu    = (const float*)d_in[6];
    const float* Wa    = (const float*)d_in[7];
    const float* ba    = (const float*)d_in[8];
    const float* gamma = (const float*)d_in[9];
    const float* beta  = (const float*)d_in[10];
    float* out = (float*)d_out;

    float* h  = (float*)d_ws;           // [BN, 64]
    float* y1 = h + 8388608;            // [BN, 64]

    const float* U1   = subU + 8388608; // sub_U[1] (branch 0 is dead code)
    const int*   idx0 = idx;
    const int*   idx1 = idx + BNROW;

    kA<<<2048, 256, 0, stream>>>(input, Wd, bd, h);
    kB<<<2048, 256, 0, stream>>>(h, U1, idx0, Wa, ba, gamma, beta, y1);
    kC<<<2048, 256, 0, stream>>>(h, y1, idx1, Wu, bu, out);
}